// Round 8
// baseline (109.921 us; speedup 1.0000x reference)
//
#include <hip/hip_runtime.h>
#include <math.h>

// Problem constants
#define SEQ    2048
#define ROT    32
#define ROWS_PER_BLOCK 64
#define NTILES (131072 / ROWS_PER_BLOCK)   // 2048 blocks

#define AS1 __attribute__((address_space(1)))
#define AS3 __attribute__((address_space(3)))

// ---------------------------------------------------------------------------
// Setup kernel v4: W = 32 * (A @ r_matrix).
// R DMA'd into LDS concurrently with the scan (drained by the 2nd barrier).
// Scan is 2-wide ILP: both steps' operands read in ONE latency window,
// step-(k+1) inputs patched in registers on index collision, writes applied
// in program order -> exact sequential semantics, half the chain latency.
// ---------------------------------------------------------------------------
__global__ __launch_bounds__(256) void build_w_kernel(
    const float* __restrict__ thetas,
    const float* __restrict__ theta_scale,
    const float* __restrict__ R,        // r_matrix, 64x64 row-major
    const int*   __restrict__ pairs,    // 32 x 2
    float*       __restrict__ W)        // out: 64x64 row-major
{
    __shared__ float A[64 * 65];        // +1 pad: conflict-free row reads
    __shared__ float Rs[64 * 64];       // R staged async, overlapped with scan
    __shared__ float Cs[ROT], Ss[ROT];
    __shared__ int   Pi[ROT], Pj[ROT];
    const int t    = threadIdx.x;
    const int wave = t >> 6;
    const int lane = t & 63;

    #pragma unroll
    for (int i = 0; i < 16; ++i) {
        int e = i * 256 + t;
        int r = e >> 6, c = e & 63;
        A[r * 65 + c] = (r == c) ? 1.0f : 0.0f;
    }
    if (t < ROT) {                      // precompute rotation params
        float th = thetas[t] * theta_scale[0];
        float sv, cv;
        sincosf(th, &sv, &cv);
        Cs[t] = cv; Ss[t] = sv;
        Pi[t] = pairs[2 * t]; Pj[t] = pairs[2 * t + 1];
    }
    __syncthreads();                    // A init + params visible

    // ---- issue async R staging NOW: DMA overlaps the scan below ----
    #pragma unroll
    for (int i = 0; i < 4; ++i) {
        int ri  = i * 4 + wave;              // region 0..15 -> rows 4ri..4ri+3
        int row = ri * 4 + (lane >> 4);
        const float* gp = R + row * 64 + (lane & 15) * 4;
        __builtin_amdgcn_global_load_lds((const AS1 unsigned int*)gp,
                                         (AS3 unsigned int*)&Rs[ri * 256], 16, 0, 0);
    }

    if (t < 64) {                       // 2-wide sequential scan
        float* Ar = &A[t * 65];
        for (int k = 0; k < ROT; k += 2) {
            int i0 = Pi[k],     j0 = Pj[k];
            int i1 = Pi[k + 1], j1 = Pj[k + 1];
            float c0 = Cs[k],     s0 = Ss[k];
            float c1 = Cs[k + 1], s1 = Ss[k + 1];
            // one latency window for all four operands
            float ai = Ar[i0], aj = Ar[j0], bi = Ar[i1], bj = Ar[j1];
            // step k  (i==j: net effect is col <- s*orig, see ref write order)
            float ni, nj;
            if (i0 != j0) { ni = c0 * ai + s0 * aj; nj = c0 * aj - s0 * ai; }
            else          { ni = s0 * ai; nj = ni; }
            // patch step k+1 inputs on collision (register fixup)
            if      (i1 == i0) bi = ni; else if (i1 == j0) bi = nj;
            if      (j1 == i0) bj = ni; else if (j1 == j0) bj = nj;
            // step k+1
            float mi, mj;
            if (i1 != j1) { mi = c1 * bi + s1 * bj; mj = c1 * bj - s1 * bi; }
            else          { mi = s1 * bi; mj = mi; }
            // program-order writes: later writes override = sequential semantics
            Ar[i0] = ni; Ar[j0] = nj;
            Ar[i1] = mi; Ar[j1] = mj;
        }
    }
    __syncthreads();                    // drains R DMA + scan writes

    const int r = (blockIdx.x << 2) + (t >> 6);   // 16 blocks * 4 rows
    const int c = t & 63;
    const float* Ar = &A[r * 65];                  // wave-uniform -> broadcast
    float acc = 0.0f;
    #pragma unroll 8
    for (int k = 0; k < 64; ++k)
        acc = fmaf(Ar[k], Rs[k * 64 + c], acc);    // lane=c stride-1: 2-way, free
    W[r * 64 + c] = 32.0f * acc;                   // fold *sqrt(1024)
}

// ---------------------------------------------------------------------------
// Main kernel v5: 64 rows/block, 2048 blocks, 256 threads, ~17 KB LDS,
// 8 blocks/CU. X read directly from global (no LDS staging); W LDS-staged
// via global_load_lds. v5: X prefetch depth 2 before the barrier; k-loop
// software-pipelines the next-kk X loads.
// ---------------------------------------------------------------------------
__global__ __launch_bounds__(256) void rotary_main_kernel(
    const float* __restrict__ x,
    const float* __restrict__ W,
    const float* __restrict__ inv_freq,
    float*       __restrict__ out)
{
    __shared__ float Ws[64 * 64];      // 16 KB, row-major
    __shared__ float SCc[4 * 32];      // cos per (pos-group, d)
    __shared__ float SCs[4 * 32];      // sin per (pos-group, d)

    const int T    = blockIdx.x;
    const int t    = threadIdx.x;
    const int wave = t >> 6;
    const int lane = t & 63;

    // ---- issue async W staging first ----
    #pragma unroll
    for (int i = 0; i < 4; ++i) {
        int ri  = i * 4 + wave;              // region 0..15 -> rows 4ri..4ri+3
        int row = ri * 4 + (lane >> 4);
        const float* gp = W + row * 64 + (lane & 15) * 4;
        __builtin_amdgcn_global_load_lds((const AS1 unsigned int*)gp,
                                         (AS3 unsigned int*)&Ws[ri * 256], 16, 0, 0);
    }
    // ---- sincos for the 4 positions covered by this tile (VALU, overlaps) ----
    if (t < 128) {
        int pg = t >> 5, d = t & 31;
        int pos = (T * 4 + pg) & (SEQ - 1);  // position = global_row/16 mod SEQ
        float sv, cv;
        sincosf((float)pos * inv_freq[d], &sv, &cv);
        SCc[t] = cv;
        SCs[t] = sv;
    }

    // ---- prefetch kk=0,1 X into VGPRs BEFORE the barrier ----
    const int rp = t >> 3;             // 0..31 -> rows 2rp, 2rp+1
    const int cg = t & 7;              // 0..7
    const int r0 = rp * 2;
    const float* xr0 = x + (size_t)T * (ROWS_PER_BLOCK * 64) + r0 * 64;
    const float* xr1 = xr0 + 64;
    float4 p0a = *(const float4*)(xr0);
    float4 p0b = *(const float4*)(xr1);
    float4 p1a = *(const float4*)(xr0 + 4);
    float4 p1b = *(const float4*)(xr1 + 4);

    __syncthreads();                   // drains W DMA (and X prefetch)

    float acc[2][8];
    #pragma unroll
    for (int m = 0; m < 2; ++m)
        #pragma unroll
        for (int j = 0; j < 8; ++j) acc[m][j] = 0.0f;

    #pragma unroll 4
    for (int kk = 0; kk < 16; ++kk) {  // 4 k per iteration, X pipelined depth-2
        const float4 xv0 = p0a;
        const float4 xv1 = p0b;
        p0a = p1a; p0b = p1b;
        if (kk < 14) {                 // issue kk+2 loads ahead of the FMAs
            p1a = *(const float4*)(xr0 + ((kk + 2) << 2));
            p1b = *(const float4*)(xr1 + ((kk + 2) << 2));
        }
        float4 wv[8];
        #pragma unroll
        for (int r = 0; r < 4; ++r) {
            wv[2 * r]     = *(const float4*)&Ws[(4 * kk + r) * 64 + cg * 8];
            wv[2 * r + 1] = *(const float4*)&Ws[(4 * kk + r) * 64 + cg * 8 + 4];
        }
        const float xa[2][4] = {{xv0.x, xv0.y, xv0.z, xv0.w},
                                {xv1.x, xv1.y, xv1.z, xv1.w}};
        #pragma unroll
        for (int m = 0; m < 2; ++m)
            #pragma unroll
            for (int r = 0; r < 4; ++r) {
                const float4 w0 = wv[2 * r], w1 = wv[2 * r + 1];
                const float xs = xa[m][r];
                acc[m][0] = fmaf(xs, w0.x, acc[m][0]);
                acc[m][1] = fmaf(xs, w0.y, acc[m][1]);
                acc[m][2] = fmaf(xs, w0.z, acc[m][2]);
                acc[m][3] = fmaf(xs, w0.w, acc[m][3]);
                acc[m][4] = fmaf(xs, w1.x, acc[m][4]);
                acc[m][5] = fmaf(xs, w1.y, acc[m][5]);
                acc[m][6] = fmaf(xs, w1.z, acc[m][6]);
                acc[m][7] = fmaf(xs, w1.w, acc[m][7]);
            }
    }

    // ---- RoPE epilogue in registers; coalesced 16B stores ----
    const int scb = (r0 >> 4) * 32 + cg * 4;   // pos-group (r0 even: rows never
    const float4 cv = *(const float4*)&SCc[scb];  // cross a 16-row boundary)
    const float4 sv = *(const float4*)&SCs[scb];
    const float cs4[4] = {cv.x, cv.y, cv.z, cv.w};
    const float sn4[4] = {sv.x, sv.y, sv.z, sv.w};

    float* og = out + (size_t)T * (ROWS_PER_BLOCK * 64);
    #pragma unroll
    for (int m = 0; m < 2; ++m) {
        int row = r0 + m;
        float o1[4], o2[4];
        #pragma unroll
        for (int d = 0; d < 4; ++d) {
            float a = acc[m][2 * d];       // even col -> x1
            float b = acc[m][2 * d + 1];   // odd col  -> x2
            o1[d] = a * cs4[d] - b * sn4[d];
            o2[d] = a * sn4[d] + b * cs4[d];
        }
        *(float4*)&og[row * 64 + cg * 4]      = make_float4(o1[0], o1[1], o1[2], o1[3]);
        *(float4*)&og[row * 64 + 32 + cg * 4] = make_float4(o2[0], o2[1], o2[2], o2[3]);
    }
}

extern "C" void kernel_launch(void* const* d_in, const int* in_sizes, int n_in,
                              void* d_out, int out_size, void* d_ws, size_t ws_size,
                              hipStream_t stream) {
    const float* x           = (const float*)d_in[0];
    const float* thetas      = (const float*)d_in[1];
    const float* theta_scale = (const float*)d_in[2];
    const float* r_matrix    = (const float*)d_in[3];
    const float* inv_freq    = (const float*)d_in[4];
    const int*   pairs       = (const int*)d_in[5];
    float*       out         = (float*)d_out;
    float*       W           = (float*)d_ws;   // 64*64 floats = 16 KB scratch

    build_w_kernel<<<16, 256, 0, stream>>>(thetas, theta_scale, r_matrix, pairs, W);
    rotary_main_kernel<<<NTILES, 256, 0, stream>>>(x, W, inv_freq, out);
}

// Round 9
// 108.737 us; speedup vs baseline: 1.0109x; 1.0109x over previous
//
#include <hip/hip_runtime.h>
#include <math.h>

// Problem constants
#define SEQ    2048
#define ROT    32
#define ROWS_PER_BLOCK 64
#define NTILES (131072 / ROWS_PER_BLOCK)   // 2048 blocks

#define AS1 __attribute__((address_space(1)))
#define AS3 __attribute__((address_space(3)))

// ---------------------------------------------------------------------------
// Setup kernel v3 (measured-best, R7): W = 32 * (A @ r_matrix).
// R is DMA'd into LDS via global_load_lds issued AFTER the first barrier,
// so the cold R fetch runs concurrently with the 32-step scan chain; the
// second barrier drains both. Scan is the simple 1-wide chain (the 2-wide
// ILP variant of R8 regressed: collision-patch cndmask chains serialized).
// ---------------------------------------------------------------------------
__global__ __launch_bounds__(256) void build_w_kernel(
    const float* __restrict__ thetas,
    const float* __restrict__ theta_scale,
    const float* __restrict__ R,        // r_matrix, 64x64 row-major
    const int*   __restrict__ pairs,    // 32 x 2
    float*       __restrict__ W)        // out: 64x64 row-major
{
    __shared__ float A[64 * 65];        // +1 pad: conflict-free row reads
    __shared__ float Rs[64 * 64];       // R staged async, overlapped with scan
    __shared__ float Cs[ROT], Ss[ROT];
    __shared__ int   Pi[ROT], Pj[ROT];
    const int t    = threadIdx.x;
    const int wave = t >> 6;
    const int lane = t & 63;

    #pragma unroll
    for (int i = 0; i < 16; ++i) {
        int e = i * 256 + t;
        int r = e >> 6, c = e & 63;
        A[r * 65 + c] = (r == c) ? 1.0f : 0.0f;
    }
    if (t < ROT) {                      // precompute rotation params
        float th = thetas[t] * theta_scale[0];
        float sv, cv;
        sincosf(th, &sv, &cv);
        Cs[t] = cv; Ss[t] = sv;
        Pi[t] = pairs[2 * t]; Pj[t] = pairs[2 * t + 1];
    }
    __syncthreads();                    // A init + params visible

    // ---- issue async R staging NOW: DMA overlaps the scan below ----
    #pragma unroll
    for (int i = 0; i < 4; ++i) {
        int ri  = i * 4 + wave;              // region 0..15 -> rows 4ri..4ri+3
        int row = ri * 4 + (lane >> 4);
        const float* gp = R + row * 64 + (lane & 15) * 4;
        __builtin_amdgcn_global_load_lds((const AS1 unsigned int*)gp,
                                         (AS3 unsigned int*)&Rs[ri * 256], 16, 0, 0);
    }

    if (t < 64) {                       // 32-step sequential scan, pure LDS
        float* Ar = &A[t * 65];
        for (int k = 0; k < ROT; ++k) {
            int i = Pi[k], j = Pj[k];
            float c = Cs[k], s = Ss[k];
            float ai = Ar[i], aj = Ar[j];
            if (i != j) { Ar[i] = c * ai + s * aj; Ar[j] = c * aj - s * ai; }
            else        { Ar[i] = s * ai; }   // ref: set(ni) overwritten by set(nj)=xi*s
        }
    }
    __syncthreads();                    // drains R DMA + scan writes

    const int r = (blockIdx.x << 2) + (t >> 6);   // 16 blocks * 4 rows
    const int c = t & 63;
    const float* Ar = &A[r * 65];                  // wave-uniform -> broadcast
    float acc = 0.0f;
    #pragma unroll 8
    for (int k = 0; k < 64; ++k)
        acc = fmaf(Ar[k], Rs[k * 64 + c], acc);    // lane=c stride-1: 2-way, free
    W[r * 64 + c] = 32.0f * acc;                   // fold *sqrt(1024)
}

// ---------------------------------------------------------------------------
// Main kernel v4 (measured-best, R7): 64 rows/block, 2048 blocks, 256 thr,
// ~17 KB LDS, 8 blocks/CU. X read directly from global (no LDS staging);
// W LDS-staged via global_load_lds. kk=0 X float4 pair prefetched into
// VGPRs BEFORE the barrier (X and W latencies overlap, drained together);
// k-loop software-pipelines the next-kk X loads (depth 1 — depth 2 of R8
// regressed).
// ---------------------------------------------------------------------------
__global__ __launch_bounds__(256) void rotary_main_kernel(
    const float* __restrict__ x,
    const float* __restrict__ W,
    const float* __restrict__ inv_freq,
    float*       __restrict__ out)
{
    __shared__ float Ws[64 * 64];      // 16 KB, row-major
    __shared__ float SCc[4 * 32];      // cos per (pos-group, d)
    __shared__ float SCs[4 * 32];      // sin per (pos-group, d)

    const int T    = blockIdx.x;
    const int t    = threadIdx.x;
    const int wave = t >> 6;
    const int lane = t & 63;

    // ---- issue async W staging first ----
    #pragma unroll
    for (int i = 0; i < 4; ++i) {
        int ri  = i * 4 + wave;              // region 0..15 -> rows 4ri..4ri+3
        int row = ri * 4 + (lane >> 4);
        const float* gp = W + row * 64 + (lane & 15) * 4;
        __builtin_amdgcn_global_load_lds((const AS1 unsigned int*)gp,
                                         (AS3 unsigned int*)&Ws[ri * 256], 16, 0, 0);
    }
    // ---- sincos for the 4 positions covered by this tile (VALU, overlaps) ----
    if (t < 128) {
        int pg = t >> 5, d = t & 31;
        int pos = (T * 4 + pg) & (SEQ - 1);  // position = global_row/16 mod SEQ
        float sv, cv;
        sincosf((float)pos * inv_freq[d], &sv, &cv);
        SCc[t] = cv;
        SCs[t] = sv;
    }

    // ---- prefetch kk=0 X into VGPRs BEFORE the barrier ----
    const int rp = t >> 3;             // 0..31 -> rows 2rp, 2rp+1
    const int cg = t & 7;              // 0..7
    const int r0 = rp * 2;
    const float* xr0 = x + (size_t)T * (ROWS_PER_BLOCK * 64) + r0 * 64;
    const float* xr1 = xr0 + 64;
    float4 nx0 = *(const float4*)(xr0);
    float4 nx1 = *(const float4*)(xr1);

    __syncthreads();                   // drains W DMA (and X prefetch)

    float acc[2][8];
    #pragma unroll
    for (int m = 0; m < 2; ++m)
        #pragma unroll
        for (int j = 0; j < 8; ++j) acc[m][j] = 0.0f;

    #pragma unroll 4
    for (int kk = 0; kk < 16; ++kk) {  // 4 k per iteration, X pipelined
        const float4 xv0 = nx0;
        const float4 xv1 = nx1;
        if (kk < 15) {                 // issue next-kk loads ahead of the FMAs
            nx0 = *(const float4*)(xr0 + ((kk + 1) << 2));
            nx1 = *(const float4*)(xr1 + ((kk + 1) << 2));
        }
        float4 wv[8];
        #pragma unroll
        for (int r = 0; r < 4; ++r) {
            wv[2 * r]     = *(const float4*)&Ws[(4 * kk + r) * 64 + cg * 8];
            wv[2 * r + 1] = *(const float4*)&Ws[(4 * kk + r) * 64 + cg * 8 + 4];
        }
        const float xa[2][4] = {{xv0.x, xv0.y, xv0.z, xv0.w},
                                {xv1.x, xv1.y, xv1.z, xv1.w}};
        #pragma unroll
        for (int m = 0; m < 2; ++m)
            #pragma unroll
            for (int r = 0; r < 4; ++r) {
                const float4 w0 = wv[2 * r], w1 = wv[2 * r + 1];
                const float xs = xa[m][r];
                acc[m][0] = fmaf(xs, w0.x, acc[m][0]);
                acc[m][1] = fmaf(xs, w0.y, acc[m][1]);
                acc[m][2] = fmaf(xs, w0.z, acc[m][2]);
                acc[m][3] = fmaf(xs, w0.w, acc[m][3]);
                acc[m][4] = fmaf(xs, w1.x, acc[m][4]);
                acc[m][5] = fmaf(xs, w1.y, acc[m][5]);
                acc[m][6] = fmaf(xs, w1.z, acc[m][6]);
                acc[m][7] = fmaf(xs, w1.w, acc[m][7]);
            }
    }

    // ---- RoPE epilogue in registers; coalesced 16B stores ----
    const int scb = (r0 >> 4) * 32 + cg * 4;   // pos-group (r0 even: rows never
    const float4 cv = *(const float4*)&SCc[scb];  // cross a 16-row boundary)
    const float4 sv = *(const float4*)&SCs[scb];
    const float cs4[4] = {cv.x, cv.y, cv.z, cv.w};
    const float sn4[4] = {sv.x, sv.y, sv.z, sv.w};

    float* og = out + (size_t)T * (ROWS_PER_BLOCK * 64);
    #pragma unroll
    for (int m = 0; m < 2; ++m) {
        int row = r0 + m;
        float o1[4], o2[4];
        #pragma unroll
        for (int d = 0; d < 4; ++d) {
            float a = acc[m][2 * d];       // even col -> x1
            float b = acc[m][2 * d + 1];   // odd col  -> x2
            o1[d] = a * cs4[d] - b * sn4[d];
            o2[d] = a * sn4[d] + b * cs4[d];
        }
        *(float4*)&og[row * 64 + cg * 4]      = make_float4(o1[0], o1[1], o1[2], o1[3]);
        *(float4*)&og[row * 64 + 32 + cg * 4] = make_float4(o2[0], o2[1], o2[2], o2[3]);
    }
}

extern "C" void kernel_launch(void* const* d_in, const int* in_sizes, int n_in,
                              void* d_out, int out_size, void* d_ws, size_t ws_size,
                              hipStream_t stream) {
    const float* x           = (const float*)d_in[0];
    const float* thetas      = (const float*)d_in[1];
    const float* theta_scale = (const float*)d_in[2];
    const float* r_matrix    = (const float*)d_in[3];
    const float* inv_freq    = (const float*)d_in[4];
    const int*   pairs       = (const int*)d_in[5];
    float*       out         = (float*)d_out;
    float*       W           = (float*)d_ws;   // 64*64 floats = 16 KB scratch

    build_w_kernel<<<16, 256, 0, stream>>>(thetas, theta_scale, r_matrix, pairs, W);
    rotary_main_kernel<<<NTILES, 256, 0, stream>>>(x, W, inv_freq, out);
}